// Round 7
// baseline (162.708 us; speedup 1.0000x reference)
//
#include <hip/hip_runtime.h>
#include <hip/hip_bf16.h>

// Problem constants
#define VD 160           // vol D=H=W
#define OD 128           // output crop size
#define CROP0 16         // (160-128)/2
#define FSZ 11           // cropped field size
#define RAWSZ 15         // raw field size
#define NBATCH 4
#define ODQ 4            // outputs per thread along od

// Eg global table: [od][oh][c][12]  (12-float channel stride, 36/pair)
#define EGC 12
#define EGP 36           // floats per (od,oh) pair
#define NSLICE 32        // field-block slices per channel

// ---------------------------------------------------------------------------
// Kernel 1: blocks 0..95 = field smooth + Eg table (c = bx/32, slice = bx%32);
// block 96 = Rodrigues/theta.
// Eg[od][oh][c][xi] = 80 * (z,y)-bilinear of smoothed disp field at x-knot xi.
// ---------------------------------------------------------------------------
__global__ __launch_bounds__(256) void prep_kernel(
        const float* __restrict__ rot, const float* __restrict__ scale,
        const float* __restrict__ shift,
        const float* __restrict__ dz, const float* __restrict__ dy,
        const float* __restrict__ dx,
        float* __restrict__ theta, float* __restrict__ Eg) {
    const int tid = threadIdx.x;
    const int bx  = blockIdx.x;

    if (bx == 96) {
        int n = tid;
        if (n >= NBATCH) return;
        float rx = rot[n*3+0], ry = rot[n*3+1], rz = rot[n*3+2];
        float t2 = rx*rx + ry*ry + rz*rz;
        const float eps = 1e-6f;
        float th = sqrtf(fmaxf(t2, eps));
        float inv = 1.0f / (th + eps);
        float wx = rx*inv, wy = ry*inv, wz = rz*inv;
        float c = cosf(th), s = sinf(th), k = 1.0f - c;
        float R[9];
        if (t2 > eps) {
            R[0] = c + wx*wx*k;      R[1] = wx*wy*k - wz*s;  R[2] = wy*s + wx*wz*k;
            R[3] = wz*s + wx*wy*k;   R[4] = c + wy*wy*k;     R[5] = -wx*s + wy*wz*k;
            R[6] = -wy*s + wx*wz*k;  R[7] = wx*s + wy*wz*k;  R[8] = c + wz*wz*k;
        } else {
            R[0] = 1.0f; R[1] = -rz;  R[2] = ry;
            R[3] = rz;   R[4] = 1.0f; R[5] = -rx;
            R[6] = -ry;  R[7] = rx;   R[8] = 1.0f;
        }
        for (int i = 0; i < 3; ++i) {
            for (int j = 0; j < 3; ++j)
                theta[n*12 + i*4 + j] = R[i*3 + j] * scale[n*3 + j];
            theta[n*12 + i*4 + 3] = shift[n*3 + i];
        }
        return;
    }

    const int chan  = bx >> 5;          // 0..2
    const int slice = bx & 31;          // 0..31

    // ---- smooth the 15^3 field in LDS (redundant per slice, cheap) ----
    __shared__ float bufA[RAWSZ*RAWSZ*RAWSZ];
    __shared__ float bufB[RAWSZ*RAWSZ*RAWSZ];
    const float* raw = (chan == 0) ? dz : (chan == 1) ? dy : dx;
    const int NTOT = RAWSZ*RAWSZ*RAWSZ;   // 3375

    for (int i = tid; i < NTOT; i += 256)
        bufA[i] = (raw[i] - 0.5f) * 4.0f;
    __syncthreads();

    float* src = bufA;
    float* dst = bufB;
    for (int it = 0; it < 4; ++it) {
        for (int ax = 0; ax < 3; ++ax) {
            const int stride = (ax == 0) ? RAWSZ*RAWSZ : (ax == 1) ? RAWSZ : 1;
            for (int i = tid; i < NTOT; i += 256) {
                int z = i / (RAWSZ*RAWSZ);
                int r = i % (RAWSZ*RAWSZ);
                int y = r / RAWSZ;
                int x = r % RAWSZ;
                int c = (ax == 0) ? z : (ax == 1) ? y : x;
                float s = 0.0f;
                #pragma unroll
                for (int t = -2; t <= 2; ++t) {
                    int cc = min(max(c + t, 0), RAWSZ - 1);
                    s += src[i + (cc - c) * stride];
                }
                dst[i] = s * 0.2f;
            }
            __syncthreads();
            float* tmp = src; src = dst; dst = tmp;
        }
    }
    // src now holds the smoothed 15^3 field; cropped view = src[.+2][.+2][.+2]

    // ---- Eg for this slice: 512 (od,oh) pairs, 12 x-knot values each ----
    for (int p = slice*512 + tid; p < slice*512 + 512; p += 256) {
        const int od = p >> 7;
        const int oh = p & 127;
        const int d_ = od + CROP0;
        const int h_ = oh + CROP0;

        // resize coords (z from od, y from oh)
        float sz = fmaf((float)d_ + 0.5f, (float)FSZ / (float)VD, -0.5f);
        sz = fminf(fmaxf(sz, 0.0f), (float)(FSZ - 1));
        float szf = floorf(sz);
        int   zi0 = (int)szf;
        int   zi1 = min(zi0 + 1, FSZ - 1);
        float zw  = sz - szf;

        float sy = fmaf((float)h_ + 0.5f, (float)FSZ / (float)VD, -0.5f);
        sy = fminf(fmaxf(sy, 0.0f), (float)(FSZ - 1));
        float syf = floorf(sy);
        int   yi0 = (int)syf;
        int   yi1 = min(yi0 + 1, FSZ - 1);
        float yw  = sy - syf;

        const float w00 = (1.0f-zw)*(1.0f-yw) * 80.0f;
        const float w01 = (1.0f-zw)*yw * 80.0f;
        const float w10 = zw*(1.0f-yw) * 80.0f;
        const float w11 = zw*yw * 80.0f;

        const float* r00 = src + (zi0+2)*(RAWSZ*RAWSZ) + (yi0+2)*RAWSZ + 2;
        const float* r01 = src + (zi0+2)*(RAWSZ*RAWSZ) + (yi1+2)*RAWSZ + 2;
        const float* r10 = src + (zi1+2)*(RAWSZ*RAWSZ) + (yi0+2)*RAWSZ + 2;
        const float* r11 = src + (zi1+2)*(RAWSZ*RAWSZ) + (yi1+2)*RAWSZ + 2;

        float vbuf[EGC];
        #pragma unroll
        for (int xi = 0; xi < FSZ; ++xi)
            vbuf[xi] = r00[xi]*w00 + r01[xi]*w01 + r10[xi]*w10 + r11[xi]*w11;
        vbuf[11] = vbuf[10];   // pad (never read)

        float* dstp = Eg + (size_t)p*EGP + chan*EGC;
        #pragma unroll
        for (int q = 0; q < 3; ++q) {
            float4 f4 = make_float4(vbuf[4*q], vbuf[4*q+1], vbuf[4*q+2], vbuf[4*q+3]);
            __builtin_memcpy(dstp + 4*q, &f4, sizeof(float4));
        }
    }
}

// ---------------------------------------------------------------------------
// Kernel 2: main sampler.
// Wave lane map = 16(ow) x 4(oh); block = 512 thr = 8 waves (2wx x 2wh x 2wd);
// block tile = 32(w) x 8(h) x 8(d); each thread does ODQ=4 od's.
// e-slab = straight copy of Eg[odb..+8][ohb..+8][3][12] (8*8*36 floats).
// LDS pair stride 36 -> hl groups on banks {0,4,8,12}: conflict-free.
// grid = (OD/32, OD/8, (OD/8)*NBATCH).
// ---------------------------------------------------------------------------
__global__ __launch_bounds__(512) void sample_kernel(
        const float* __restrict__ vol, const float* __restrict__ theta,
        const float* __restrict__ Eg, float* __restrict__ out) {
    __shared__ float e[8*8*EGP];       // 2304 floats = 9216 B

    const int tid  = threadIdx.x;
    const int lane = tid & 63;
    const int wl   = lane & 15;        // x within wave patch
    const int hl   = lane >> 4;        // y within wave patch (0..3)
    const int wv   = tid >> 6;         // wave id 0..7
    const int wx   = wv & 1;
    const int wh   = (wv >> 1) & 1;
    const int wd   = wv >> 2;          // 0..1

    const int ow_l = (wx << 4) | wl;       // 0..31
    const int oh_l = (wh << 2) | hl;       // 0..7
    const int ow   = (blockIdx.x << 5) | ow_l;
    const int oh   = (blockIdx.y << 3) | oh_l;
    const int ohb  = blockIdx.y << 3;
    const int odb  = (blockIdx.z & 15) << 3;   // od block base (0..120)
    const int n    = blockIdx.z >> 4;

    // ---- copy e-slab: 8 od rows x (8 oh x 36 floats = 288 floats = 72 f4) ----
    for (int t = tid; t < 8*72; t += 512) {
        const int od_l = t / 72;
        const int r    = t - od_l*72;
        const float* g = Eg + ((size_t)(odb + od_l)*128 + ohb)*EGP + 4*r;
        float4 f4;
        __builtin_memcpy(&f4, g, sizeof(float4));
        __builtin_memcpy(&e[od_l*288 + 4*r], &f4, sizeof(float4));
    }
    __syncthreads();

    const int w_ = ow + CROP0;
    const int h_ = oh + CROP0;

    const float x = fmaf(2.0f * (float)w_ + 1.0f, 1.0f / (float)VD, -1.0f);
    const float y = fmaf(2.0f * (float)h_ + 1.0f, 1.0f / (float)VD, -1.0f);

    // x-knot: xi0 <= 9 for valid w_, xi1 = xi0+1 always
    float s = fmaf((float)w_ + 0.5f, (float)FSZ / (float)VD, -0.5f);
    s = fminf(fmaxf(s, 0.0f), (float)(FSZ - 1));
    const float sf = floorf(s);
    const int   xi0 = (int)sf;
    const float xw  = s - sf;

    const float* th = theta + n*12;
    const float cx = fmaf(th[0]*x + th[1]*y + th[3], 80.0f, 79.5f);
    const float cy = fmaf(th[4]*x + th[5]*y + th[7], 80.0f, 79.5f);
    const float cz = fmaf(th[8]*x + th[9]*y + th[11], 80.0f, 79.5f);
    const float tz0 = th[2] * 80.0f, tz1 = th[6] * 80.0f, tz2 = th[10] * 80.0f;

    const float* v = vol + (size_t)n * (VD*VD*VD);

    // single vaddr for all e reads; (k,c) parts are immediate byte offsets
    const float* ebase = &e[((wd << 2)*8 + oh_l)*EGP + xi0];

    #pragma unroll
    for (int k = 0; k < ODQ; ++k) {
        const int od = odb + ((wd << 2) | k);
        const int d_ = od + CROP0;
        const float z = fmaf(2.0f * (float)d_ + 1.0f, 1.0f / (float)VD, -1.0f);

        const float ex0 = ebase[k*288          ], ex1 = ebase[k*288           + 1];
        const float ey0 = ebase[k*288 + EGC    ], ey1 = ebase[k*288 + EGC     + 1];
        const float ez0 = ebase[k*288 + 2*EGC  ], ez1 = ebase[k*288 + 2*EGC   + 1];
        const float d80x = fmaf(ex1 - ex0, xw, ex0);
        const float d80y = fmaf(ey1 - ey0, xw, ey0);
        const float d80z = fmaf(ez1 - ez0, xw, ez0);

        const float xs = fmaf(tz0, z, cx) + d80x;
        const float ys = fmaf(tz1, z, cy) + d80y;
        const float zs = fmaf(tz2, z, cz) + d80z;

        const float x0f = floorf(xs), y0f = floorf(ys), z0f = floorf(zs);
        const float fx = xs - x0f, fy = ys - y0f, fz = zs - z0f;
        const int ix0 = (int)x0f, iy0 = (int)y0f, iz0 = (int)z0f;
        const int ix1 = ix0 + 1,  iy1 = iy0 + 1,  iz1 = iz0 + 1;

        const float WX0 = ((unsigned)ix0 < (unsigned)VD) ? (1.0f - fx) : 0.0f;
        const float WX1 = ((unsigned)ix1 < (unsigned)VD) ? fx          : 0.0f;
        const float WY0 = ((unsigned)iy0 < (unsigned)VD) ? (1.0f - fy) : 0.0f;
        const float WY1 = ((unsigned)iy1 < (unsigned)VD) ? fy          : 0.0f;
        const float WZ0 = ((unsigned)iz0 < (unsigned)VD) ? (1.0f - fz) : 0.0f;
        const float WZ1 = ((unsigned)iz1 < (unsigned)VD) ? fz          : 0.0f;

        const int xc0 = min(max(ix0, 0), VD-1), xc1 = min(max(ix1, 0), VD-1);
        const int yc0 = min(max(iy0, 0), VD-1), yc1 = min(max(iy1, 0), VD-1);
        const int zc0 = min(max(iz0, 0), VD-1), zc1 = min(max(iz1, 0), VD-1);

        // one dwordx2 covers both x-taps; fold x-selection into wA/wB
        const int base = min(xc0, VD-2);
        const bool hi0 = (xc0 != base);
        const bool hi1 = (xc1 != base);
        const float wA = (hi0 ? 0.0f : WX0) + (hi1 ? 0.0f : WX1);
        const float wB = (hi0 ? WX0 : 0.0f) + (hi1 ? WX1 : 0.0f);

        const int b00 = (zc0*VD + yc0)*VD + base;
        const int b01 = (zc0*VD + yc1)*VD + base;
        const int b10 = (zc1*VD + yc0)*VD + base;
        const int b11 = (zc1*VD + yc1)*VD + base;

        float2 p00, p01, p10, p11;
        __builtin_memcpy(&p00, v + b00, sizeof(float2));
        __builtin_memcpy(&p01, v + b01, sizeof(float2));
        __builtin_memcpy(&p10, v + b10, sizeof(float2));
        __builtin_memcpy(&p11, v + b11, sizeof(float2));

        const float r00 = p00.x*wA + p00.y*wB;
        const float r01 = p01.x*wA + p01.y*wB;
        const float r10 = p10.x*wA + p10.y*wB;
        const float r11 = p11.x*wA + p11.y*wB;
        const float r = (r00*WY0 + r01*WY1)*WZ0 + (r10*WY0 + r11*WY1)*WZ1;

        out[(((size_t)n*OD + od)*OD + oh)*OD + ow] = r;
    }
}

// ---------------------------------------------------------------------------
extern "C" void kernel_launch(void* const* d_in, const int* in_sizes, int n_in,
                              void* d_out, int out_size, void* d_ws, size_t ws_size,
                              hipStream_t stream) {
    const float* vol   = (const float*)d_in[0];
    const float* rot   = (const float*)d_in[1];
    const float* scale = (const float*)d_in[2];
    const float* shift = (const float*)d_in[3];
    const float* dz    = (const float*)d_in[4];
    const float* dy    = (const float*)d_in[5];
    const float* dx    = (const float*)d_in[6];
    float* out = (float*)d_out;

    float* ws     = (float*)d_ws;
    float* theta  = ws;         // 48 floats
    float* Eg     = ws + 64;    // 128*128*36 = 589,824 floats (2.36 MB)

    prep_kernel<<<97, 256, 0, stream>>>(rot, scale, shift, dz, dy, dx,
                                        theta, Eg);
    dim3 grid(OD/32, OD/8, (OD/8)*NBATCH);
    sample_kernel<<<grid, 512, 0, stream>>>(vol, theta, Eg, out);
}